// Round 11
// baseline (150.424 us; speedup 1.0000x reference)
//
#include <hip/hip_runtime.h>

// LightGlue attention block: B=4, N=4096, D=256.
//   q = desc0@Wq^T+bq; k,v = desc1@{Wk,Wv}^T+{bk,bv}
//   att = softmax(q k^T / 16) v ; out = att@Wo^T + bo
// ws layout (bytes):
//   q     [0,        8M)   bf16 [b][n][d] row-major
//   k     [8M,      16M)   bf16 [b][n][d] row-major
//   v     [16M,     24M)   bf16 BLOCKED [b][kkb 64][d 256][kk 64]
//   part0 [24M,     32M)   bf16 [q 16384][d 256]  (UNNORMALIZED O partial)
//   part1 [32M,     40M)   bf16 [q 16384][d 256]
//   lw    [40M, 40M+128K)  f32  [2][16384]

typedef __attribute__((ext_vector_type(8))) __bf16 bf16x8;
typedef __attribute__((ext_vector_type(4))) float f32x4;
typedef __attribute__((ext_vector_type(16))) float f32x16;
typedef __attribute__((ext_vector_type(4))) unsigned int u32x4;
typedef __attribute__((ext_vector_type(2))) unsigned int u32x2;
typedef __attribute__((ext_vector_type(4))) unsigned short us16x4;

__device__ __forceinline__ unsigned short f2bf(float f) {
  unsigned u = __builtin_bit_cast(unsigned, f);
  u += 0x7FFFu + ((u >> 16) & 1u);  // RNE
  return (unsigned short)(u >> 16);
}
__device__ __forceinline__ unsigned pk2(float a, float b) {
  return (unsigned)f2bf(a) | ((unsigned)f2bf(b) << 16);
}
__device__ __forceinline__ unsigned cvtpk(float lo, float hi) {
  unsigned r;
  asm("v_cvt_pk_bf16_f32 %0, %1, %2" : "=v"(r) : "v"(lo), "v"(hi));
  return r;
}
__device__ __forceinline__ float bf2f(unsigned short s) {
  return __builtin_bit_cast(float, ((unsigned)s) << 16);
}
__device__ __forceinline__ int swz4(int r) { return (r ^ (r >> 2)) & 3; }
__device__ __forceinline__ bf16x8 ldbf16(const void* p) {
  return __builtin_bit_cast(bf16x8, *(const u32x4*)p);
}
__device__ __forceinline__ f32x4 mfma16(bf16x8 a, bf16x8 b, f32x4 c) {
  return __builtin_amdgcn_mfma_f32_16x16x32_bf16(a, b, c, 0, 0, 0);
}
__device__ __forceinline__ f32x16 mfma32(bf16x8 a, bf16x8 b, f32x16 c) {
  return __builtin_amdgcn_mfma_f32_32x32x16_bf16(a, b, c, 0, 0, 0);
}
__device__ __forceinline__ void gld16(void* lds, const void* gsrc) {
  __builtin_amdgcn_global_load_lds(
      (const __attribute__((address_space(1))) unsigned int*)gsrc,
      (__attribute__((address_space(3))) unsigned int*)lds, 16, 0, 0);
}

// ---------------- fused QKV projection (R10, proven) ----------------
__global__ __launch_bounds__(256, 4) void qkv_k(
    const float* __restrict__ desc0, const float* __restrict__ desc1,
    const float* __restrict__ Wq, const float* __restrict__ bq,
    const float* __restrict__ Wk, const float* __restrict__ bk,
    const float* __restrict__ Wv, const float* __restrict__ bv,
    unsigned short* __restrict__ qout, unsigned short* __restrict__ kout,
    unsigned short* __restrict__ vout) {
  __shared__ __align__(16) unsigned short Al[2][64 * 32];
  __shared__ __align__(16) unsigned short W1l[2][64 * 32];
  __shared__ __align__(16) unsigned short W2l[2][64 * 32];
  __shared__ float b1l[64], b2l[64];
  const int tid = threadIdx.x;
  const int w = tid >> 6, l = tid & 63, g = l >> 4, c = l & 15;
  const int bid = blockIdx.x;
  const bool iskv = bid >= 1024;
  const int bb = iskv ? bid - 1024 : bid;
  const int mt = bb & 255, nq = bb >> 8;
  const int row0 = mt * 64, n0 = nq * 64;
  const float* A = iskv ? desc1 : desc0;
  const float* W1 = iskv ? Wk : Wq;
  if (tid < 64) {
    b1l[tid] = (iskv ? bk : bq)[n0 + tid];
    if (iskv) b2l[tid] = bv[n0 + tid];
  }

  const int sr = tid >> 2, seg = tid & 3;
  const int ssw = swz4(sr);

#define CONV8(dst, X, Y)                                                              \
  {                                                                                   \
    u32x4 _v;                                                                         \
    _v[0] = pk2((X).x, (X).y); _v[1] = pk2((X).z, (X).w);                             \
    _v[2] = pk2((Y).x, (Y).y); _v[3] = pk2((Y).z, (Y).w);                             \
    *(u32x4*)(dst) = _v;                                                              \
  }

  {  // prologue: stage chunk 0 -> buf 0
    const float* ap = A + (size_t)(row0 + sr) * 256 + seg * 8;
    float4 ax = *(const float4*)ap, ay = *(const float4*)(ap + 4);
    CONV8(&Al[0][sr * 32 + ((seg ^ ssw) << 3)], ax, ay);
    const float* wp = W1 + (size_t)(n0 + sr) * 256 + seg * 8;
    float4 wx = *(const float4*)wp, wy = *(const float4*)(wp + 4);
    CONV8(&W1l[0][sr * 32 + ((seg ^ ssw) << 3)], wx, wy);
    if (iskv) {
      const float* wp2 = Wv + (size_t)(n0 + sr) * 256 + seg * 8;
      float4 w2x = *(const float4*)wp2, w2y = *(const float4*)(wp2 + 4);
      CONV8(&W2l[0][sr * 32 + ((seg ^ ssw) << 3)], w2x, w2y);
    }
  }
  __syncthreads();

  f32x4 acc1[4], acc2[4];
#pragma unroll
  for (int jt = 0; jt < 4; ++jt) {
    acc1[jt] = (f32x4){0.f, 0.f, 0.f, 0.f};
    acc2[jt] = (f32x4){0.f, 0.f, 0.f, 0.f};
  }

#pragma unroll 1
  for (int ch = 0; ch < 8; ++ch) {
    const int cur = ch & 1;
    const bool pre = (ch + 1 < 8);
    float4 ax, ay, wx, wy, w2x, w2y;
    if (pre) {
      const int ko = (ch + 1) * 32 + seg * 8;
      const float* ap = A + (size_t)(row0 + sr) * 256 + ko;
      ax = *(const float4*)ap; ay = *(const float4*)(ap + 4);
      const float* wp = W1 + (size_t)(n0 + sr) * 256 + ko;
      wx = *(const float4*)wp; wy = *(const float4*)(wp + 4);
      if (iskv) {
        const float* wp2 = Wv + (size_t)(n0 + sr) * 256 + ko;
        w2x = *(const float4*)wp2; w2y = *(const float4*)(wp2 + 4);
      }
    }
    const int ra = w * 16 + c;
    bf16x8 af = ldbf16(&Al[cur][ra * 32 + ((g ^ swz4(ra)) << 3)]);
#pragma unroll
    for (int jt = 0; jt < 4; ++jt) {
      const int j = jt * 16 + c;
      bf16x8 w1f = ldbf16(&W1l[cur][j * 32 + ((g ^ swz4(j)) << 3)]);
      acc1[jt] = mfma16(af, w1f, acc1[jt]);
    }
    if (iskv) {
#pragma unroll
      for (int jt = 0; jt < 4; ++jt) {
        const int j = jt * 16 + c;
        bf16x8 w2f = ldbf16(&W2l[cur][j * 32 + ((g ^ swz4(j)) << 3)]);
        acc2[jt] = mfma16(af, w2f, acc2[jt]);
      }
    }
    if (pre) {
      CONV8(&Al[1 - cur][sr * 32 + ((seg ^ ssw) << 3)], ax, ay);
      CONV8(&W1l[1 - cur][sr * 32 + ((seg ^ ssw) << 3)], wx, wy);
      if (iskv) CONV8(&W2l[1 - cur][sr * 32 + ((seg ^ ssw) << 3)], w2x, w2y);
    }
    __syncthreads();
  }
#undef CONV8

  unsigned short* o1 = iskv ? kout : qout;
  const int rloc = w * 16 + (g << 2);
#pragma unroll
  for (int jt = 0; jt < 4; ++jt) {
    const int col = n0 + jt * 16 + c;
    const float bvv = b1l[jt * 16 + c];
#pragma unroll
    for (int r = 0; r < 4; ++r)
      o1[(size_t)(row0 + rloc + r) * 256 + col] = f2bf(acc1[jt][r] + bvv);
  }
  if (iskv) {
    const int n = row0 + rloc;
    const int b = n >> 12, nl = n & 4095;
#pragma unroll
    for (int jt = 0; jt < 4; ++jt) {
      const int col = n0 + jt * 16 + c;
      const float bvv = b2l[jt * 16 + c];
      us16x4 pk;
      pk[0] = f2bf(acc2[jt][0] + bvv); pk[1] = f2bf(acc2[jt][1] + bvv);
      pk[2] = f2bf(acc2[jt][2] + bvv); pk[3] = f2bf(acc2[jt][3] + bvv);
      *(us16x4*)(vout + (size_t)b * 1048576 + (size_t)(nl >> 6) * 16384 + col * 64 + (nl & 63)) = pk;
    }
  }
}

// ---------------- final projection (R10, proven) ----------------
template <int IN_MODE>
__global__ __launch_bounds__(256, 4) void projo_k(const unsigned short* __restrict__ Ain,
                                                  const float* __restrict__ W,
                                                  const float* __restrict__ bias,
                                                  float* __restrict__ Cout,
                                                  const float* __restrict__ lwA) {
  __shared__ __align__(16) unsigned short Al[2][64 * 32];
  __shared__ __align__(16) unsigned short Wl[2][64 * 32];
  __shared__ float biasl[64];
  const int tid = threadIdx.x;
  const int w = tid >> 6, l = tid & 63, g = l >> 4, c = l & 15;
  const int mt = blockIdx.x & 255, nq = blockIdx.x >> 8;
  const int row0 = mt * 64, n0 = nq * 64;
  if (tid < 64) biasl[tid] = bias[n0 + tid];

  const int sr = tid >> 2, seg = tid & 3;
  const int ssw = swz4(sr);

  float ainv;
  {
    const int grow = row0 + sr;
    float lt = lwA[grow];
    if (IN_MODE == 2) lt += lwA[16384 + grow];
    ainv = 1.f / lt;
  }

#define ACONV(dst, M0, M1)                                                          \
  {                                                                                 \
    u32x4 _v;                                                                       \
    _Pragma("unroll") for (int i = 0; i < 4; ++i) {                                 \
      float _lo = bf2f((unsigned short)((M0)[i] & 0xFFFF));                         \
      float _hi = bf2f((unsigned short)((M0)[i] >> 16));                            \
      if (IN_MODE == 2) {                                                           \
        _lo += bf2f((unsigned short)((M1)[i] & 0xFFFF));                            \
        _hi += bf2f((unsigned short)((M1)[i] >> 16));                               \
      }                                                                             \
      _v[i] = pk2(_lo * ainv, _hi * ainv);                                          \
    }                                                                               \
    *(u32x4*)(dst) = _v;                                                            \
  }

  {
    const unsigned short* ap = Ain + (size_t)(row0 + sr) * 256 + seg * 8;
    u32x4 a0 = *(const u32x4*)ap;
    u32x4 a1 = (IN_MODE == 2) ? *(const u32x4*)(ap + 4194304) : a0;
    ACONV(&Al[0][sr * 32 + ((seg ^ ssw) << 3)], a0, a1);
    const float* wp = W + (size_t)(n0 + sr) * 256 + seg * 8;
    float4 x = *(const float4*)wp, y = *(const float4*)(wp + 4);
    u32x4 v; v[0] = pk2(x.x, x.y); v[1] = pk2(x.z, x.w); v[2] = pk2(y.x, y.y); v[3] = pk2(y.z, y.w);
    *(u32x4*)&Wl[0][sr * 32 + ((seg ^ ssw) << 3)] = v;
  }
  __syncthreads();

  f32x4 acc[4];
#pragma unroll
  for (int jt = 0; jt < 4; ++jt) acc[jt] = (f32x4){0.f, 0.f, 0.f, 0.f};

#pragma unroll 1
  for (int ch = 0; ch < 8; ++ch) {
    const int cur = ch & 1;
    const bool pre = (ch + 1 < 8);
    float4 wx, wy; u32x4 abv, abv2;
    if (pre) {
      const int ko = (ch + 1) * 32 + seg * 8;
      const unsigned short* ap = Ain + (size_t)(row0 + sr) * 256 + ko;
      abv = *(const u32x4*)ap;
      if (IN_MODE == 2) abv2 = *(const u32x4*)(ap + 4194304);
      const float* wp = W + (size_t)(n0 + sr) * 256 + ko;
      wx = *(const float4*)wp; wy = *(const float4*)(wp + 4);
    }
    const int ra = w * 16 + c;
    bf16x8 af = ldbf16(&Al[cur][ra * 32 + ((g ^ swz4(ra)) << 3)]);
#pragma unroll
    for (int jt = 0; jt < 4; ++jt) {
      const int j = jt * 16 + c;
      bf16x8 bfr = ldbf16(&Wl[cur][j * 32 + ((g ^ swz4(j)) << 3)]);
      acc[jt] = mfma16(af, bfr, acc[jt]);
    }
    if (pre) {
      ACONV(&Al[1 - cur][sr * 32 + ((seg ^ ssw) << 3)], abv, abv2);
      u32x4 vw; vw[0] = pk2(wx.x, wx.y); vw[1] = pk2(wx.z, wx.w); vw[2] = pk2(wy.x, wy.y); vw[3] = pk2(wy.z, wy.w);
      *(u32x4*)&Wl[1 - cur][sr * 32 + ((seg ^ ssw) << 3)] = vw;
    }
    __syncthreads();
  }
#undef ACONV

#pragma unroll
  for (int jt = 0; jt < 4; ++jt) {
    const int col = n0 + jt * 16 + c;
    const float bv = biasl[jt * 16 + c];
    const int rloc = w * 16 + (g << 2);
#pragma unroll
    for (int r = 0; r < 4; ++r)
      Cout[(size_t)(row0 + rloc + r) * 256 + col] = acc[jt][r] + bv;
  }
}

// ---------------- flash attention: single-barrier merged-phase (K,V,P all LDS dbuf) ----
// Grid 128*NS, 512 thr (8 waves), 1 block/CU. KVBLK=64.
// iter t: STAGEK(t+1)->K[(t+1)&1], STAGEV(t)->V[t&1] (DMA, lands at barrier);
//   QK(t) [K LDS t&1] + PV(t-1) [V,P (t-1)&1] in one merged MFMA+LDS region;
//   SM(t); Pw(t)->P[t&1]; __syncthreads.
// V staged one iter ahead of its PV use => dbuf suffices; P write/read opposite halves.
// LDS exactly 160K: K 2x32K @0 | V 2x32K @65536 | P 2x16K @131072.
// Epilogue: PV(NT-1); Lb reuses free P half @131072; transpose T reuses [0,128K).
template <int NS>
__global__ __launch_bounds__(512, 2) void attn_k(const unsigned short* __restrict__ qg,
                                                 const unsigned short* __restrict__ kg,
                                                 const unsigned short* __restrict__ vg,
                                                 unsigned short* __restrict__ part,
                                                 float* __restrict__ lw) {
  __shared__ __align__(16) unsigned char smem[163840];
  const int tid = threadIdx.x, w = tid >> 6, l = tid & 63;
  const int l31 = l & 31, h5 = l >> 5;
  const int qt = w >> 1, hf = w & 1;   // QK role
  const int dh = w >> 1, qh = w & 1;   // PV role
  const int bid = blockIdx.x;
  const int b4 = bid & 3;
  const int s = (NS == 2) ? ((bid >> 2) & 1) : 0;
  const int qtl = (NS == 2) ? (bid >> 3) : (bid >> 2);
  const int q0 = qtl * 128;
  const int NT = (NS == 2) ? 32 : 64;

  const unsigned short* kb = kg + (size_t)b4 * 1048576 + (size_t)s * 524288;
  const unsigned short* vb = vg + (size_t)b4 * 1048576 + (size_t)s * 32 * 16384;

  bf16x8 qf[16];
  {
    const unsigned short* qp = qg + ((size_t)b4 * 4096 + q0 + qt * 32 + l31) * 256;
#pragma unroll
    for (int kst = 0; kst < 16; ++kst) qf[kst] = ldbf16(qp + kst * 16 + h5 * 8);
  }

  f32x16 o[4];
#pragma unroll
  for (int d = 0; d < 4; ++d)
#pragma unroll
    for (int r = 0; r < 16; ++r) o[d][r] = 0.f;
  float l_run = 0.f;

  int goffK[4], goffV[4];
#pragma unroll
  for (int i = 0; i < 4; ++i) {
    const int sl = i * 512 + tid;
    const int kk = sl >> 5, ch = sl & 31;
    goffK[i] = kk * 256 + ((ch ^ (kk & 31)) << 3);
    const int r = sl >> 4, p16 = sl & 15;
    const int x = p16 ^ (r & 15);
    goffV[i] = (2 * r + (x >> 3)) * 64 + ((x & 7) << 3);
  }
#define STAGEK(buf, t1)                                                                  \
  {                                                                                      \
    const unsigned short* _ks = kb + (size_t)(t1) * 16384;                               \
    _Pragma("unroll") for (int i = 0; i < 4; ++i)                                        \
        gld16(smem + (buf) * 32768 + i * 8192 + w * 1024, _ks + goffK[i]);               \
  }
#define STAGEV(buf, t1)                                                                  \
  {                                                                                      \
    const unsigned short* _vs = vb + (size_t)(t1) * 16384;                               \
    _Pragma("unroll") for (int i = 0; i < 4; ++i)                                        \
        gld16(smem + 65536 + (buf) * 32768 + i * 8192 + w * 1024, _vs + goffV[i]);       \
  }
#define PVBODY(pbuf)                                                                     \
  {                                                                                      \
    const unsigned char* Vc = smem + 65536 + (pbuf) * 32768;                             \
    bf16x8 va[8];                                                                        \
    _Pragma("unroll") for (int dd = 0; dd < 2; ++dd) {                                   \
      const int dm = dh * 64 + dd * 32 + l31;                                            \
      const int rr = dm >> 1;                                                            \
      const unsigned char* Vr = Vc + rr * 256;                                           \
      const int xb = (dm & 1) * 8;                                                       \
      _Pragma("unroll") for (int kst = 0; kst < 4; ++kst)                                \
          va[dd * 4 + kst] = ldbf16(Vr + (((xb + kst * 2 + h5) ^ (rr & 15)) << 4));      \
    }                                                                                    \
    __builtin_amdgcn_s_setprio(1);                                                       \
    _Pragma("unroll") for (int qq = 0; qq < 2; ++qq) {                                   \
      const unsigned char* Pr = smem + 131072 + (pbuf) * 16384 + (qh * 2 + qq) * 4096;   \
      bf16x8 pb[4];                                                                      \
      _Pragma("unroll") for (int kst = 0; kst < 4; ++kst)                                \
          pb[kst] = ldbf16(Pr + l31 * 128 + (((kst * 2 + h5) ^ (l31 & 7)) << 4));        \
      _Pragma("unroll") for (int dd = 0; dd < 2; ++dd)                                   \
          _Pragma("unroll") for (int kst = 0; kst < 4; ++kst)                            \
              o[dd * 2 + qq] = mfma32(va[dd * 4 + kst], pb[kst], o[dd * 2 + qq]);        \
    }                                                                                    \
    __builtin_amdgcn_s_setprio(0);                                                       \
  }

  STAGEK(0, 0);
  __syncthreads();

  const float alpha = 0.09016844f;  // log2(e)/16
  const int kkr = hf * 32 + l31;

#pragma unroll 1
  for (int t = 0; t < NT; ++t) {
    const int cur = t & 1;
    if (t + 1 < NT) STAGEK(1 - cur, t + 1);
    STAGEV(cur, t);  // V(t) used by PV(t) NEXT iter; lands at this iter's barrier

    // ---- merged MFMA region: QK(t) + PV(t-1) (independent; scheduler interleaves)
    const unsigned char* Kc = smem + cur * 32768 + kkr * 512;
    f32x16 sa, sb;
#pragma unroll
    for (int r = 0; r < 16; ++r) { sa[r] = 0.f; sb[r] = 0.f; }
    __builtin_amdgcn_s_setprio(1);
#pragma unroll
    for (int kst = 0; kst < 16; ++kst) {
      bf16x8 kf = ldbf16(Kc + (((kst * 2 + h5) ^ l31) << 4));
      if (kst & 1) sb = mfma32(kf, qf[kst], sb);
      else         sa = mfma32(kf, qf[kst], sa);
    }
    __builtin_amdgcn_s_setprio(0);
    if (t > 0) PVBODY(1 - cur);

    // ---- softmax (fixed-norm) + P pack/write -> P[cur]
    float p[16];
#pragma unroll
    for (int r = 0; r < 16; ++r) p[r] = exp2f((sa[r] + sb[r]) * alpha);
    float ls = ((p[0] + p[1]) + (p[2] + p[3])) + ((p[4] + p[5]) + (p[6] + p[7])) +
               (((p[8] + p[9]) + (p[10] + p[11])) + ((p[12] + p[13]) + (p[14] + p[15])));
    l_run += ls;  // lane-local; cross-half reduce after loop

    unsigned u[8];
#pragma unroll
    for (int i = 0; i < 8; ++i) u[i] = cvtpk(p[2 * i], p[2 * i + 1]);
    unsigned char* Pq = smem + 131072 + cur * 16384 + qt * 4096;
#pragma unroll
    for (int j = 0; j < 4; ++j) {
      u32x2 dv; dv[0] = u[2 * j]; dv[1] = u[2 * j + 1];
      *(u32x2*)(Pq + l31 * 128 + (((j + 4 * hf) ^ (l31 & 7)) << 4) + h5 * 8) = dv;
    }

    // single barrier: publishes P(t), K(t+1), V(t); drains stage DMA
    __syncthreads();
  }
  PVBODY((NT - 1) & 1);  // epilogue PV for last tile
#undef STAGEK
#undef STAGEV
#undef PVBODY

  l_run += __shfl_xor(l_run, 32);

  // Lb in free P half (P[(NT-2)&1] = buf0 @131072; done being read before final barrier)
  float* Lb = (float*)(smem + 131072);
  if (l < 32) Lb[(qt * 2 + hf) * 32 + l31] = l_run;
  __syncthreads();  // epilogue PV reads done everywhere; Lb visible

  unsigned char* T = smem + w * 16384;
#pragma unroll
  for (int dd = 0; dd < 2; ++dd)
#pragma unroll
    for (int qq = 0; qq < 2; ++qq)
#pragma unroll
      for (int rg = 0; rg < 4; ++rg) {
        f32x4 wv;
        wv[0] = o[dd * 2 + qq][4 * rg + 0]; wv[1] = o[dd * 2 + qq][4 * rg + 1];
        wv[2] = o[dd * 2 + qq][4 * rg + 2]; wv[3] = o[dd * 2 + qq][4 * rg + 3];
        const int qloc = qq * 32 + l31;
        const int c16 = dd * 8 + rg * 2 + h5;
        *(f32x4*)(T + qloc * 256 + ((c16 ^ (qloc & 15)) << 4)) = wv;
      }
  asm volatile("s_waitcnt lgkmcnt(0)" ::: "memory");
  __builtin_amdgcn_sched_barrier(0);
  {
    const int qloc = l;
    f32x4 rv[16];
#pragma unroll
    for (int c16 = 0; c16 < 16; ++c16)
      rv[c16] = *(const f32x4*)(T + qloc * 256 + ((c16 ^ (qloc & 15)) << 4));
    unsigned short* op = part + (size_t)s * 4194304 +
                         ((size_t)b4 * 4096 + q0 + qh * 64 + qloc) * 256 + dh * 64;
#pragma unroll
    for (int i = 0; i < 8; ++i) {
      u32x4 ov;
      ov[0] = pk2(rv[2 * i][0], rv[2 * i][1]);
      ov[1] = pk2(rv[2 * i][2], rv[2 * i][3]);
      ov[2] = pk2(rv[2 * i + 1][0], rv[2 * i + 1][1]);
      ov[3] = pk2(rv[2 * i + 1][2], rv[2 * i + 1][3]);
      *(u32x4*)(op + i * 8) = ov;
    }
  }
  if (hf == 0 && l < 32) {
    const float lt = Lb[(qt * 2) * 32 + l31] + Lb[(qt * 2 + 1) * 32 + l31];
    lw[(size_t)s * 16384 + (size_t)b4 * 4096 + q0 + qt * 32 + l31] = lt;
  }
}

extern "C" void kernel_launch(void* const* d_in, const int* in_sizes, int n_in,
                              void* d_out, int out_size, void* d_ws, size_t ws_size,
                              hipStream_t stream) {
  (void)in_sizes; (void)n_in; (void)out_size;
  const float* desc0 = (const float*)d_in[0];
  const float* desc1 = (const float*)d_in[1];
  const float* Wq = (const float*)d_in[2];
  const float* bq = (const float*)d_in[3];
  const float* Wk = (const float*)d_in[4];
  const float* bk = (const float*)d_in[5];
  const float* Wv = (const float*)d_in[6];
  const float* bv = (const float*)d_in[7];
  const float* Wo = (const float*)d_in[8];
  const float* bo = (const float*)d_in[9];

  unsigned char* ws = (unsigned char*)d_ws;
  unsigned short* qw = (unsigned short*)(ws);
  unsigned short* kw = (unsigned short*)(ws + 8388608);
  unsigned short* vw = (unsigned short*)(ws + 16777216);
  unsigned short* part = (unsigned short*)(ws + 25165824);
  float* lwp = (float*)(ws + 41943040);

  const bool two = (ws_size >= 42008576ull);

  qkv_k<<<2048, 256, 0, stream>>>(desc0, desc1, Wq, bq, Wk, bk, Wv, bv, qw, kw, vw);
  if (two) {
    attn_k<2><<<256, 512, 0, stream>>>(qw, kw, vw, part, lwp);
    projo_k<2><<<1024, 256, 0, stream>>>(part, Wo, bo, (float*)d_out, lwp);
  } else {
    lwp = (float*)(ws + 33554432);
    attn_k<1><<<128, 512, 0, stream>>>(qw, kw, vw, part, lwp);
    projo_k<3><<<1024, 256, 0, stream>>>(part, Wo, bo, (float*)d_out, lwp);
  }
}

// Round 12
// 122.171 us; speedup vs baseline: 1.2313x; 1.2313x over previous
//
#include <hip/hip_runtime.h>

// LightGlue attention block: B=4, N=4096, D=256.
//   q = desc0@Wq^T+bq; k,v = desc1@{Wk,Wv}^T+{bk,bv}
//   att = softmax(q k^T / 16) v ; out = att@Wo^T + bo
// ws layout (bytes):
//   q     [0,        8M)   bf16 [b][n][d] row-major
//   k     [8M,      16M)   bf16 [b][n][d] row-major
//   v     [16M,     24M)   bf16 BLOCKED [b][kkb 64][d 256][kk 64]
//   part0 [24M,     32M)   bf16 [q 16384][d 256]  (UNNORMALIZED O partial)
//   part1 [32M,     40M)   bf16 [q 16384][d 256]
//   lw    [40M, 40M+128K)  f32  [2][16384]

typedef __attribute__((ext_vector_type(8))) __bf16 bf16x8;
typedef __attribute__((ext_vector_type(4))) float f32x4;
typedef __attribute__((ext_vector_type(16))) float f32x16;
typedef __attribute__((ext_vector_type(4))) unsigned int u32x4;
typedef __attribute__((ext_vector_type(2))) unsigned int u32x2;
typedef __attribute__((ext_vector_type(4))) unsigned short us16x4;

__device__ __forceinline__ unsigned short f2bf(float f) {
  unsigned u = __builtin_bit_cast(unsigned, f);
  u += 0x7FFFu + ((u >> 16) & 1u);  // RNE
  return (unsigned short)(u >> 16);
}
__device__ __forceinline__ unsigned pk2(float a, float b) {
  return (unsigned)f2bf(a) | ((unsigned)f2bf(b) << 16);
}
__device__ __forceinline__ unsigned cvtpk(float lo, float hi) {
  unsigned r;
  asm("v_cvt_pk_bf16_f32 %0, %1, %2" : "=v"(r) : "v"(lo), "v"(hi));
  return r;
}
__device__ __forceinline__ float bf2f(unsigned short s) {
  return __builtin_bit_cast(float, ((unsigned)s) << 16);
}
__device__ __forceinline__ int swz4(int r) { return (r ^ (r >> 2)) & 3; }
__device__ __forceinline__ bf16x8 ldbf16(const void* p) {
  return __builtin_bit_cast(bf16x8, *(const u32x4*)p);
}
__device__ __forceinline__ f32x4 mfma16(bf16x8 a, bf16x8 b, f32x4 c) {
  return __builtin_amdgcn_mfma_f32_16x16x32_bf16(a, b, c, 0, 0, 0);
}
__device__ __forceinline__ f32x16 mfma32(bf16x8 a, bf16x8 b, f32x16 c) {
  return __builtin_amdgcn_mfma_f32_32x32x16_bf16(a, b, c, 0, 0, 0);
}
__device__ __forceinline__ void gld16(void* lds, const void* gsrc) {
  __builtin_amdgcn_global_load_lds(
      (const __attribute__((address_space(1))) unsigned int*)gsrc,
      (__attribute__((address_space(3))) unsigned int*)lds, 16, 0, 0);
}

// ---------------- fused QKV projection (R10, proven) ----------------
__global__ __launch_bounds__(256, 4) void qkv_k(
    const float* __restrict__ desc0, const float* __restrict__ desc1,
    const float* __restrict__ Wq, const float* __restrict__ bq,
    const float* __restrict__ Wk, const float* __restrict__ bk,
    const float* __restrict__ Wv, const float* __restrict__ bv,
    unsigned short* __restrict__ qout, unsigned short* __restrict__ kout,
    unsigned short* __restrict__ vout) {
  __shared__ __align__(16) unsigned short Al[2][64 * 32];
  __shared__ __align__(16) unsigned short W1l[2][64 * 32];
  __shared__ __align__(16) unsigned short W2l[2][64 * 32];
  __shared__ float b1l[64], b2l[64];
  const int tid = threadIdx.x;
  const int w = tid >> 6, l = tid & 63, g = l >> 4, c = l & 15;
  const int bid = blockIdx.x;
  const bool iskv = bid >= 1024;
  const int bb = iskv ? bid - 1024 : bid;
  const int mt = bb & 255, nq = bb >> 8;
  const int row0 = mt * 64, n0 = nq * 64;
  const float* A = iskv ? desc1 : desc0;
  const float* W1 = iskv ? Wk : Wq;
  if (tid < 64) {
    b1l[tid] = (iskv ? bk : bq)[n0 + tid];
    if (iskv) b2l[tid] = bv[n0 + tid];
  }

  const int sr = tid >> 2, seg = tid & 3;
  const int ssw = swz4(sr);

#define CONV8(dst, X, Y)                                                              \
  {                                                                                   \
    u32x4 _v;                                                                         \
    _v[0] = pk2((X).x, (X).y); _v[1] = pk2((X).z, (X).w);                             \
    _v[2] = pk2((Y).x, (Y).y); _v[3] = pk2((Y).z, (Y).w);                             \
    *(u32x4*)(dst) = _v;                                                              \
  }

  {  // prologue: stage chunk 0 -> buf 0
    const float* ap = A + (size_t)(row0 + sr) * 256 + seg * 8;
    float4 ax = *(const float4*)ap, ay = *(const float4*)(ap + 4);
    CONV8(&Al[0][sr * 32 + ((seg ^ ssw) << 3)], ax, ay);
    const float* wp = W1 + (size_t)(n0 + sr) * 256 + seg * 8;
    float4 wx = *(const float4*)wp, wy = *(const float4*)(wp + 4);
    CONV8(&W1l[0][sr * 32 + ((seg ^ ssw) << 3)], wx, wy);
    if (iskv) {
      const float* wp2 = Wv + (size_t)(n0 + sr) * 256 + seg * 8;
      float4 w2x = *(const float4*)(wp2), w2y = *(const float4*)(wp2 + 4);
      CONV8(&W2l[0][sr * 32 + ((seg ^ ssw) << 3)], w2x, w2y);
    }
  }
  __syncthreads();

  f32x4 acc1[4], acc2[4];
#pragma unroll
  for (int jt = 0; jt < 4; ++jt) {
    acc1[jt] = (f32x4){0.f, 0.f, 0.f, 0.f};
    acc2[jt] = (f32x4){0.f, 0.f, 0.f, 0.f};
  }

#pragma unroll 1
  for (int ch = 0; ch < 8; ++ch) {
    const int cur = ch & 1;
    const bool pre = (ch + 1 < 8);
    float4 ax, ay, wx, wy, w2x, w2y;
    if (pre) {
      const int ko = (ch + 1) * 32 + seg * 8;
      const float* ap = A + (size_t)(row0 + sr) * 256 + ko;
      ax = *(const float4*)ap; ay = *(const float4*)(ap + 4);
      const float* wp = W1 + (size_t)(n0 + sr) * 256 + ko;
      wx = *(const float4*)wp; wy = *(const float4*)(wp + 4);
      if (iskv) {
        const float* wp2 = Wv + (size_t)(n0 + sr) * 256 + ko;
        w2x = *(const float4*)wp2; w2y = *(const float4*)(wp2 + 4);
      }
    }
    const int ra = w * 16 + c;
    bf16x8 af = ldbf16(&Al[cur][ra * 32 + ((g ^ swz4(ra)) << 3)]);
#pragma unroll
    for (int jt = 0; jt < 4; ++jt) {
      const int j = jt * 16 + c;
      bf16x8 w1f = ldbf16(&W1l[cur][j * 32 + ((g ^ swz4(j)) << 3)]);
      acc1[jt] = mfma16(af, w1f, acc1[jt]);
    }
    if (iskv) {
#pragma unroll
      for (int jt = 0; jt < 4; ++jt) {
        const int j = jt * 16 + c;
        bf16x8 w2f = ldbf16(&W2l[cur][j * 32 + ((g ^ swz4(j)) << 3)]);
        acc2[jt] = mfma16(af, w2f, acc2[jt]);
      }
    }
    if (pre) {
      CONV8(&Al[1 - cur][sr * 32 + ((seg ^ ssw) << 3)], ax, ay);
      CONV8(&W1l[1 - cur][sr * 32 + ((seg ^ ssw) << 3)], wx, wy);
      if (iskv) CONV8(&W2l[1 - cur][sr * 32 + ((seg ^ ssw) << 3)], w2x, w2y);
    }
    __syncthreads();
  }
#undef CONV8

  unsigned short* o1 = iskv ? kout : qout;
  const int rloc = w * 16 + (g << 2);
#pragma unroll
  for (int jt = 0; jt < 4; ++jt) {
    const int col = n0 + jt * 16 + c;
    const float bvv = b1l[jt * 16 + c];
#pragma unroll
    for (int r = 0; r < 4; ++r)
      o1[(size_t)(row0 + rloc + r) * 256 + col] = f2bf(acc1[jt][r] + bvv);
  }
  if (iskv) {
    const int n = row0 + rloc;
    const int b = n >> 12, nl = n & 4095;
#pragma unroll
    for (int jt = 0; jt < 4; ++jt) {
      const int col = n0 + jt * 16 + c;
      const float bvv = b2l[jt * 16 + c];
      us16x4 pk;
      pk[0] = f2bf(acc2[jt][0] + bvv); pk[1] = f2bf(acc2[jt][1] + bvv);
      pk[2] = f2bf(acc2[jt][2] + bvv); pk[3] = f2bf(acc2[jt][3] + bvv);
      *(us16x4*)(vout + (size_t)b * 1048576 + (size_t)(nl >> 6) * 16384 + col * 64 + (nl & 63)) = pk;
    }
  }
}

// ---------------- final projection (R10, proven) ----------------
template <int IN_MODE>
__global__ __launch_bounds__(256, 4) void projo_k(const unsigned short* __restrict__ Ain,
                                                  const float* __restrict__ W,
                                                  const float* __restrict__ bias,
                                                  float* __restrict__ Cout,
                                                  const float* __restrict__ lwA) {
  __shared__ __align__(16) unsigned short Al[2][64 * 32];
  __shared__ __align__(16) unsigned short Wl[2][64 * 32];
  __shared__ float biasl[64];
  const int tid = threadIdx.x;
  const int w = tid >> 6, l = tid & 63, g = l >> 4, c = l & 15;
  const int mt = blockIdx.x & 255, nq = blockIdx.x >> 8;
  const int row0 = mt * 64, n0 = nq * 64;
  if (tid < 64) biasl[tid] = bias[n0 + tid];

  const int sr = tid >> 2, seg = tid & 3;
  const int ssw = swz4(sr);

  float ainv;
  {
    const int grow = row0 + sr;
    float lt = lwA[grow];
    if (IN_MODE == 2) lt += lwA[16384 + grow];
    ainv = 1.f / lt;
  }

#define ACONV(dst, M0, M1)                                                          \
  {                                                                                 \
    u32x4 _v;                                                                       \
    _Pragma("unroll") for (int i = 0; i < 4; ++i) {                                 \
      float _lo = bf2f((unsigned short)((M0)[i] & 0xFFFF));                         \
      float _hi = bf2f((unsigned short)((M0)[i] >> 16));                            \
      if (IN_MODE == 2) {                                                           \
        _lo += bf2f((unsigned short)((M1)[i] & 0xFFFF));                            \
        _hi += bf2f((unsigned short)((M1)[i] >> 16));                               \
      }                                                                             \
      _v[i] = pk2(_lo * ainv, _hi * ainv);                                          \
    }                                                                               \
    *(u32x4*)(dst) = _v;                                                            \
  }

  {
    const unsigned short* ap = Ain + (size_t)(row0 + sr) * 256 + seg * 8;
    u32x4 a0 = *(const u32x4*)ap;
    u32x4 a1 = (IN_MODE == 2) ? *(const u32x4*)(ap + 4194304) : a0;
    ACONV(&Al[0][sr * 32 + ((seg ^ ssw) << 3)], a0, a1);
    const float* wp = W + (size_t)(n0 + sr) * 256 + seg * 8;
    float4 x = *(const float4*)wp, y = *(const float4*)(wp + 4);
    u32x4 v; v[0] = pk2(x.x, x.y); v[1] = pk2(x.z, x.w); v[2] = pk2(y.x, y.y); v[3] = pk2(y.z, y.w);
    *(u32x4*)&Wl[0][sr * 32 + ((seg ^ ssw) << 3)] = v;
  }
  __syncthreads();

  f32x4 acc[4];
#pragma unroll
  for (int jt = 0; jt < 4; ++jt) acc[jt] = (f32x4){0.f, 0.f, 0.f, 0.f};

#pragma unroll 1
  for (int ch = 0; ch < 8; ++ch) {
    const int cur = ch & 1;
    const bool pre = (ch + 1 < 8);
    float4 wx, wy; u32x4 abv, abv2;
    if (pre) {
      const int ko = (ch + 1) * 32 + seg * 8;
      const unsigned short* ap = Ain + (size_t)(row0 + sr) * 256 + ko;
      abv = *(const u32x4*)ap;
      if (IN_MODE == 2) abv2 = *(const u32x4*)(ap + 4194304);
      const float* wp = W + (size_t)(n0 + sr) * 256 + ko;
      wx = *(const float4*)wp; wy = *(const float4*)(wp + 4);
    }
    const int ra = w * 16 + c;
    bf16x8 af = ldbf16(&Al[cur][ra * 32 + ((g ^ swz4(ra)) << 3)]);
#pragma unroll
    for (int jt = 0; jt < 4; ++jt) {
      const int j = jt * 16 + c;
      bf16x8 bfr = ldbf16(&Wl[cur][j * 32 + ((g ^ swz4(j)) << 3)]);
      acc[jt] = mfma16(af, bfr, acc[jt]);
    }
    if (pre) {
      ACONV(&Al[1 - cur][sr * 32 + ((seg ^ ssw) << 3)], abv, abv2);
      u32x4 vw; vw[0] = pk2(wx.x, wx.y); vw[1] = pk2(wx.z, wx.w); vw[2] = pk2(wy.x, wy.y); vw[3] = pk2(wy.z, wy.w);
      *(u32x4*)&Wl[1 - cur][sr * 32 + ((seg ^ ssw) << 3)] = vw;
    }
    __syncthreads();
  }
#undef ACONV

#pragma unroll
  for (int jt = 0; jt < 4; ++jt) {
    const int col = n0 + jt * 16 + c;
    const float bv = biasl[jt * 16 + c];
    const int rloc = w * 16 + (g << 2);
#pragma unroll
    for (int r = 0; r < 4; ++r)
      Cout[(size_t)(row0 + rloc + r) * 256 + col] = acc[jt][r] + bv;
  }
}

// ---------------- flash attention (R10 skeleton; va V-frag reads hoisted above bar1) ----
// V[cur] is valid from iter start (staged at t-1, drained by bar2(t-1)), so its 8
// ds_read_b128 are issued right after QK to overlap the softmax VALU chain; after
// bar1 only the pb reads precede the PV MFMAs.
template <int NS>
__global__ __launch_bounds__(512, 2) void attn_k(const unsigned short* __restrict__ qg,
                                                 const unsigned short* __restrict__ kg,
                                                 const unsigned short* __restrict__ vg,
                                                 unsigned short* __restrict__ part,
                                                 float* __restrict__ lw) {
  __shared__ __align__(16) unsigned char smem[148480];
  const int tid = threadIdx.x, w = tid >> 6, l = tid & 63;
  const int l31 = l & 31, h5 = l >> 5;
  const int qt = w >> 1, hf = w & 1;   // QK role
  const int dh = w >> 1, qh = w & 1;   // PV role
  const int bid = blockIdx.x;
  const int b4 = bid & 3;
  const int s = (NS == 2) ? ((bid >> 2) & 1) : 0;
  const int qtl = (NS == 2) ? (bid >> 3) : (bid >> 2);
  const int q0 = qtl * 128;
  const int NT = (NS == 2) ? 32 : 64;

  const unsigned short* kb = kg + (size_t)b4 * 1048576 + (size_t)s * 524288;
  const unsigned short* vb = vg + (size_t)b4 * 1048576 + (size_t)s * 32 * 16384;

  bf16x8 qf[16];
  {
    const unsigned short* qp = qg + ((size_t)b4 * 4096 + q0 + qt * 32 + l31) * 256;
#pragma unroll
    for (int kst = 0; kst < 16; ++kst) qf[kst] = ldbf16(qp + kst * 16 + h5 * 8);
  }

  f32x16 o[4];
#pragma unroll
  for (int d = 0; d < 4; ++d)
#pragma unroll
    for (int r = 0; r < 16; ++r) o[d][r] = 0.f;
  float l_run = 0.f;

  int goffK[4], goffV[4];
#pragma unroll
  for (int i = 0; i < 4; ++i) {
    const int sl = i * 512 + tid;
    const int kk = sl >> 5, ch = sl & 31;
    goffK[i] = kk * 256 + ((ch ^ (kk & 31)) << 3);
    const int r = sl >> 4, p16 = sl & 15;
    const int x = p16 ^ (r & 15);
    goffV[i] = (2 * r + (x >> 3)) * 64 + ((x & 7) << 3);
  }
#define STAGE(buf, t1)                                                                   \
  {                                                                                      \
    const unsigned short* _ks = kb + (size_t)(t1) * 16384;                               \
    const unsigned short* _vs = vb + (size_t)(t1) * 16384;                               \
    _Pragma("unroll") for (int i = 0; i < 4; ++i)                                        \
        gld16(smem + (buf) * 32768 + i * 8192 + w * 1024, _ks + goffK[i]);               \
    _Pragma("unroll") for (int i = 0; i < 4; ++i)                                        \
        gld16(smem + 65536 + (buf) * 32768 + i * 8192 + w * 1024, _vs + goffV[i]);       \
  }

  STAGE(0, 0);
  __syncthreads();

  const float alpha = 0.09016844f;  // log2(e)/16
  unsigned char* Pq = smem + 131072 + qt * 4096;
  const int kkr = hf * 32 + l31;

#pragma unroll 1
  for (int t = 0; t < NT; ++t) {
    const int cur = t & 1;
    if (t + 1 < NT) STAGE(1 - cur, t + 1);

    const unsigned char* Kc = smem + cur * 32768 + kkr * 512;
    f32x16 sa, sb;
#pragma unroll
    for (int r = 0; r < 16; ++r) { sa[r] = 0.f; sb[r] = 0.f; }
    __builtin_amdgcn_s_setprio(1);
#pragma unroll
    for (int kst = 0; kst < 16; ++kst) {
      bf16x8 kf = ldbf16(Kc + (((kst * 2 + h5) ^ l31) << 4));
      if (kst & 1) sb = mfma32(kf, qf[kst], sb);
      else         sa = mfma32(kf, qf[kst], sa);
    }
    __builtin_amdgcn_s_setprio(0);

    // ---- hoisted V-frag reads (V[cur] valid since bar2 of t-1): overlap softmax VALU
    const unsigned char* Vc = smem + 65536 + cur * 32768;
    bf16x8 va[8];
#pragma unroll
    for (int dd = 0; dd < 2; ++dd) {
      const int dm = dh * 64 + dd * 32 + l31;
      const int rr = dm >> 1;
      const unsigned char* Vr = Vc + rr * 256;
      const int xb = (dm & 1) * 8;
#pragma unroll
      for (int kst = 0; kst < 4; ++kst)
        va[dd * 4 + kst] = ldbf16(Vr + (((xb + kst * 2 + h5) ^ (rr & 15)) << 4));
    }

    float p[16];
#pragma unroll
    for (int r = 0; r < 16; ++r) p[r] = exp2f((sa[r] + sb[r]) * alpha);
    float ls = ((p[0] + p[1]) + (p[2] + p[3])) + ((p[4] + p[5]) + (p[6] + p[7])) +
               (((p[8] + p[9]) + (p[10] + p[11])) + ((p[12] + p[13]) + (p[14] + p[15])));
    l_run += ls;  // lane-local; cross-half reduce hoisted to after the loop

    unsigned u[8];
#pragma unroll
    for (int i = 0; i < 8; ++i) u[i] = cvtpk(p[2 * i], p[2 * i + 1]);
#pragma unroll
    for (int j = 0; j < 4; ++j) {
      u32x2 dv; dv[0] = u[2 * j]; dv[1] = u[2 * j + 1];
      *(u32x2*)(Pq + l31 * 128 + (((j + 4 * hf) ^ (l31 & 7)) << 4) + h5 * 8) = dv;
    }

    asm volatile("s_waitcnt lgkmcnt(0)\n\ts_barrier" ::: "memory");
    __builtin_amdgcn_sched_barrier(0);

    __builtin_amdgcn_s_setprio(1);
#pragma unroll
    for (int qq = 0; qq < 2; ++qq) {
      const unsigned char* Pr = smem + 131072 + (qh * 2 + qq) * 4096;
      bf16x8 pb[4];
#pragma unroll
      for (int kst = 0; kst < 4; ++kst)
        pb[kst] = ldbf16(Pr + l31 * 128 + (((kst * 2 + h5) ^ (l31 & 7)) << 4));
#pragma unroll
      for (int dd = 0; dd < 2; ++dd)
#pragma unroll
        for (int kst = 0; kst < 4; ++kst)
          o[dd * 2 + qq] = mfma32(va[dd * 4 + kst], pb[kst], o[dd * 2 + qq]);
    }
    __builtin_amdgcn_s_setprio(0);

    __syncthreads();
  }
#undef STAGE

  l_run += __shfl_xor(l_run, 32);  // hoisted cross-half l reduce

  float* Lb = (float*)(smem + 147456);
  if (l < 32) Lb[(qt * 2 + hf) * 32 + l31] = l_run;
  __syncthreads();

  unsigned char* T = smem + w * 16384;
#pragma unroll
  for (int dd = 0; dd < 2; ++dd)
#pragma unroll
    for (int qq = 0; qq < 2; ++qq)
#pragma unroll
      for (int rg = 0; rg < 4; ++rg) {
        f32x4 wv;
        wv[0] = o[dd * 2 + qq][4 * rg + 0]; wv[1] = o[dd * 2 + qq][4 * rg + 1];
        wv[2] = o[dd * 2 + qq][4 * rg + 2]; wv[3] = o[dd * 2 + qq][4 * rg + 3];
        const int qloc = qq * 32 + l31;
        const int c16 = dd * 8 + rg * 2 + h5;
        *(f32x4*)(T + qloc * 256 + ((c16 ^ (qloc & 15)) << 4)) = wv;
      }
  asm volatile("s_waitcnt lgkmcnt(0)" ::: "memory");
  __builtin_amdgcn_sched_barrier(0);
  {
    const int qloc = l;
    f32x4 rv[16];
#pragma unroll
    for (int c16 = 0; c16 < 16; ++c16)
      rv[c16] = *(const f32x4*)(T + qloc * 256 + ((c16 ^ (qloc & 15)) << 4));
    unsigned short* op = part + (size_t)s * 4194304 +
                         ((size_t)b4 * 4096 + q0 + qh * 64 + qloc) * 256 + dh * 64;
#pragma unroll
    for (int i = 0; i < 8; ++i) {
      u32x4 ov;
      ov[0] = pk2(rv[2 * i][0], rv[2 * i][1]);
      ov[1] = pk2(rv[2 * i][2], rv[2 * i][3]);
      ov[2] = pk2(rv[2 * i + 1][0], rv[2 * i + 1][1]);
      ov[3] = pk2(rv[2 * i + 1][2], rv[2 * i + 1][3]);
      *(u32x4*)(op + i * 8) = ov;
    }
  }
  if (hf == 0 && l < 32) {
    const float lt = Lb[(qt * 2) * 32 + l31] + Lb[(qt * 2 + 1) * 32 + l31];
    lw[(size_t)s * 16384 + (size_t)b4 * 4096 + q0 + qt * 32 + l31] = lt;
  }
}

extern "C" void kernel_launch(void* const* d_in, const int* in_sizes, int n_in,
                              void* d_out, int out_size, void* d_ws, size_t ws_size,
                              hipStream_t stream) {
  (void)in_sizes; (void)n_in; (void)out_size;
  const float* desc0 = (const float*)d_in[0];
  const float* desc1 = (const float*)d_in[1];
  const float* Wq = (const float*)d_in[2];
  const float* bq = (const float*)d_in[3];
  const float* Wk = (const float*)d_in[4];
  const float* bk = (const float*)d_in[5];
  const float* Wv = (const float*)d_in[6];
  const float* bv = (const float*)d_in[7];
  const float* Wo = (const float*)d_in[8];
  const float* bo = (const float*)d_in[9];

  unsigned char* ws = (unsigned char*)d_ws;
  unsigned short* qw = (unsigned short*)(ws);
  unsigned short* kw = (unsigned short*)(ws + 8388608);
  unsigned short* vw = (unsigned short*)(ws + 16777216);
  unsigned short* part = (unsigned short*)(ws + 25165824);
  float* lwp = (float*)(ws + 41943040);

  const bool two = (ws_size >= 42008576ull);

  qkv_k<<<2048, 256, 0, stream>>>(desc0, desc1, Wq, bq, Wk, bk, Wv, bv, qw, kw, vw);
  if (two) {
    attn_k<2><<<256, 512, 0, stream>>>(qw, kw, vw, part, lwp);
    projo_k<2><<<1024, 256, 0, stream>>>(part, Wo, bo, (float*)d_out, lwp);
  } else {
    lwp = (float*)(ws + 33554432);
    attn_k<1><<<128, 512, 0, stream>>>(qw, kw, vw, part, lwp);
    projo_k<3><<<1024, 256, 0, stream>>>(part, Wo, bo, (float*)d_out, lwp);
  }
}

// Round 13
// 118.761 us; speedup vs baseline: 1.2666x; 1.0287x over previous
//
#include <hip/hip_runtime.h>

// LightGlue attention block: B=4, N=4096, D=256.
//   q = desc0@Wq^T+bq; k,v = desc1@{Wk,Wv}^T+{bk,bv}
//   att = softmax(q k^T / 16) v ; out = att@Wo^T + bo
// alpha = log2(e)/16 is folded into the Q projection (Wq,bq scaled in qkv_k).
// ws layout (bytes):
//   q     [0,        8M)   bf16 [b][n][d] row-major (PRE-SCALED by alpha)
//   k     [8M,      16M)   bf16 [b][n][d] row-major
//   v     [16M,     24M)   bf16 BLOCKED [b][kkb 64][d 256][kk 64]
//   part0 [24M,     32M)   bf16 [q 16384][d 256]  (UNNORMALIZED O partial)
//   part1 [32M,     40M)   bf16 [q 16384][d 256]
//   lw    [40M, 40M+128K)  f32  [2][16384]

typedef __attribute__((ext_vector_type(8))) __bf16 bf16x8;
typedef __attribute__((ext_vector_type(4))) float f32x4;
typedef __attribute__((ext_vector_type(16))) float f32x16;
typedef __attribute__((ext_vector_type(4))) unsigned int u32x4;
typedef __attribute__((ext_vector_type(2))) unsigned int u32x2;
typedef __attribute__((ext_vector_type(4))) unsigned short us16x4;

__device__ __forceinline__ unsigned short f2bf(float f) {
  unsigned u = __builtin_bit_cast(unsigned, f);
  u += 0x7FFFu + ((u >> 16) & 1u);  // RNE
  return (unsigned short)(u >> 16);
}
__device__ __forceinline__ unsigned pk2(float a, float b) {
  return (unsigned)f2bf(a) | ((unsigned)f2bf(b) << 16);
}
__device__ __forceinline__ unsigned cvtpk(float lo, float hi) {  // v_cvt_pk_bf16_f32: RNE, 1 op
  unsigned r;
  asm("v_cvt_pk_bf16_f32 %0, %1, %2" : "=v"(r) : "v"(lo), "v"(hi));
  return r;
}
__device__ __forceinline__ float bf2f(unsigned short s) {
  return __builtin_bit_cast(float, ((unsigned)s) << 16);
}
__device__ __forceinline__ int swz4(int r) { return (r ^ (r >> 2)) & 3; }
__device__ __forceinline__ bf16x8 ldbf16(const void* p) {
  return __builtin_bit_cast(bf16x8, *(const u32x4*)p);
}
__device__ __forceinline__ f32x4 mfma16(bf16x8 a, bf16x8 b, f32x4 c) {
  return __builtin_amdgcn_mfma_f32_16x16x32_bf16(a, b, c, 0, 0, 0);
}
__device__ __forceinline__ f32x16 mfma32(bf16x8 a, bf16x8 b, f32x16 c) {
  return __builtin_amdgcn_mfma_f32_32x32x16_bf16(a, b, c, 0, 0, 0);
}
__device__ __forceinline__ void gld16(void* lds, const void* gsrc) {
  __builtin_amdgcn_global_load_lds(
      (const __attribute__((address_space(1))) unsigned int*)gsrc,
      (__attribute__((address_space(3))) unsigned int*)lds, 16, 0, 0);
}

// ---------------- fused QKV projection (R10 structure; cvtpk staging; alpha fold) ----
__global__ __launch_bounds__(256, 4) void qkv_k(
    const float* __restrict__ desc0, const float* __restrict__ desc1,
    const float* __restrict__ Wq, const float* __restrict__ bq,
    const float* __restrict__ Wk, const float* __restrict__ bk,
    const float* __restrict__ Wv, const float* __restrict__ bv,
    unsigned short* __restrict__ qout, unsigned short* __restrict__ kout,
    unsigned short* __restrict__ vout) {
  __shared__ __align__(16) unsigned short Al[2][64 * 32];
  __shared__ __align__(16) unsigned short W1l[2][64 * 32];
  __shared__ __align__(16) unsigned short W2l[2][64 * 32];
  __shared__ float b1l[64], b2l[64];
  const int tid = threadIdx.x;
  const int w = tid >> 6, l = tid & 63, g = l >> 4, c = l & 15;
  const int bid = blockIdx.x;
  const bool iskv = bid >= 1024;
  const int bb = iskv ? bid - 1024 : bid;
  const int mt = bb & 255, nq = bb >> 8;
  const int row0 = mt * 64, n0 = nq * 64;
  const float* A = iskv ? desc1 : desc0;
  const float* W1 = iskv ? Wk : Wq;
  const float qs = iskv ? 1.f : 0.09016844f;  // alpha fold (Q path only)
  if (tid < 64) {
    b1l[tid] = (iskv ? bk : bq)[n0 + tid] * qs;
    if (iskv) b2l[tid] = bv[n0 + tid];
  }

  const int sr = tid >> 2, seg = tid & 3;
  const int ssw = swz4(sr);

#define CONV8(dst, X, Y)                                                              \
  {                                                                                   \
    u32x4 _v;                                                                         \
    _v[0] = cvtpk((X).x, (X).y); _v[1] = cvtpk((X).z, (X).w);                         \
    _v[2] = cvtpk((Y).x, (Y).y); _v[3] = cvtpk((Y).z, (Y).w);                         \
    *(u32x4*)(dst) = _v;                                                              \
  }
#define CONV8S(dst, X, Y, S)                                                          \
  {                                                                                   \
    u32x4 _v;                                                                         \
    _v[0] = cvtpk((X).x * (S), (X).y * (S)); _v[1] = cvtpk((X).z * (S), (X).w * (S)); \
    _v[2] = cvtpk((Y).x * (S), (Y).y * (S)); _v[3] = cvtpk((Y).z * (S), (Y).w * (S)); \
    *(u32x4*)(dst) = _v;                                                              \
  }

  {  // prologue: stage chunk 0 -> buf 0
    const float* ap = A + (size_t)(row0 + sr) * 256 + seg * 8;
    float4 ax = *(const float4*)ap, ay = *(const float4*)(ap + 4);
    CONV8(&Al[0][sr * 32 + ((seg ^ ssw) << 3)], ax, ay);
    const float* wp = W1 + (size_t)(n0 + sr) * 256 + seg * 8;
    float4 wx = *(const float4*)wp, wy = *(const float4*)(wp + 4);
    CONV8S(&W1l[0][sr * 32 + ((seg ^ ssw) << 3)], wx, wy, qs);
    if (iskv) {
      const float* wp2 = Wv + (size_t)(n0 + sr) * 256 + seg * 8;
      float4 w2x = *(const float4*)(wp2), w2y = *(const float4*)(wp2 + 4);
      CONV8(&W2l[0][sr * 32 + ((seg ^ ssw) << 3)], w2x, w2y);
    }
  }
  __syncthreads();

  f32x4 acc1[4], acc2[4];
#pragma unroll
  for (int jt = 0; jt < 4; ++jt) {
    acc1[jt] = (f32x4){0.f, 0.f, 0.f, 0.f};
    acc2[jt] = (f32x4){0.f, 0.f, 0.f, 0.f};
  }

#pragma unroll 1
  for (int ch = 0; ch < 8; ++ch) {
    const int cur = ch & 1;
    const bool pre = (ch + 1 < 8);
    float4 ax, ay, wx, wy, w2x, w2y;
    if (pre) {
      const int ko = (ch + 1) * 32 + seg * 8;
      const float* ap = A + (size_t)(row0 + sr) * 256 + ko;
      ax = *(const float4*)ap; ay = *(const float4*)(ap + 4);
      const float* wp = W1 + (size_t)(n0 + sr) * 256 + ko;
      wx = *(const float4*)wp; wy = *(const float4*)(wp + 4);
      if (iskv) {
        const float* wp2 = Wv + (size_t)(n0 + sr) * 256 + ko;
        w2x = *(const float4*)wp2; w2y = *(const float4*)(wp2 + 4);
      }
    }
    const int ra = w * 16 + c;
    bf16x8 af = ldbf16(&Al[cur][ra * 32 + ((g ^ swz4(ra)) << 3)]);
#pragma unroll
    for (int jt = 0; jt < 4; ++jt) {
      const int j = jt * 16 + c;
      bf16x8 w1f = ldbf16(&W1l[cur][j * 32 + ((g ^ swz4(j)) << 3)]);
      acc1[jt] = mfma16(af, w1f, acc1[jt]);
    }
    if (iskv) {
#pragma unroll
      for (int jt = 0; jt < 4; ++jt) {
        const int j = jt * 16 + c;
        bf16x8 w2f = ldbf16(&W2l[cur][j * 32 + ((g ^ swz4(j)) << 3)]);
        acc2[jt] = mfma16(af, w2f, acc2[jt]);
      }
    }
    if (pre) {
      CONV8(&Al[1 - cur][sr * 32 + ((seg ^ ssw) << 3)], ax, ay);
      CONV8S(&W1l[1 - cur][sr * 32 + ((seg ^ ssw) << 3)], wx, wy, qs);
      if (iskv) CONV8(&W2l[1 - cur][sr * 32 + ((seg ^ ssw) << 3)], w2x, w2y);
    }
    __syncthreads();
  }
#undef CONV8
#undef CONV8S

  unsigned short* o1 = iskv ? kout : qout;
  const int rloc = w * 16 + (g << 2);
#pragma unroll
  for (int jt = 0; jt < 4; ++jt) {
    const int col = n0 + jt * 16 + c;
    const float bvv = b1l[jt * 16 + c];
#pragma unroll
    for (int r = 0; r < 4; ++r)
      o1[(size_t)(row0 + rloc + r) * 256 + col] = f2bf(acc1[jt][r] + bvv);
  }
  if (iskv) {
    const int n = row0 + rloc;
    const int b = n >> 12, nl = n & 4095;
#pragma unroll
    for (int jt = 0; jt < 4; ++jt) {
      const int col = n0 + jt * 16 + c;
      const float bvv = b2l[jt * 16 + c];
      u32x2 pkv;
      pkv[0] = cvtpk(acc2[jt][0] + bvv, acc2[jt][1] + bvv);
      pkv[1] = cvtpk(acc2[jt][2] + bvv, acc2[jt][3] + bvv);
      *(u32x2*)(vout + (size_t)b * 1048576 + (size_t)(nl >> 6) * 16384 + col * 64 + (nl & 63)) = pkv;
    }
  }
}

// ---------------- final projection (R10 structure; cvtpk staging) ----------------
template <int IN_MODE>
__global__ __launch_bounds__(256, 4) void projo_k(const unsigned short* __restrict__ Ain,
                                                  const float* __restrict__ W,
                                                  const float* __restrict__ bias,
                                                  float* __restrict__ Cout,
                                                  const float* __restrict__ lwA) {
  __shared__ __align__(16) unsigned short Al[2][64 * 32];
  __shared__ __align__(16) unsigned short Wl[2][64 * 32];
  __shared__ float biasl[64];
  const int tid = threadIdx.x;
  const int w = tid >> 6, l = tid & 63, g = l >> 4, c = l & 15;
  const int mt = blockIdx.x & 255, nq = blockIdx.x >> 8;
  const int row0 = mt * 64, n0 = nq * 64;
  if (tid < 64) biasl[tid] = bias[n0 + tid];

  const int sr = tid >> 2, seg = tid & 3;
  const int ssw = swz4(sr);

  float ainv;
  {
    const int grow = row0 + sr;
    float lt = lwA[grow];
    if (IN_MODE == 2) lt += lwA[16384 + grow];
    ainv = 1.f / lt;
  }

#define ACONV(dst, M0, M1)                                                          \
  {                                                                                 \
    u32x4 _v;                                                                       \
    _Pragma("unroll") for (int i = 0; i < 4; ++i) {                                 \
      float _lo = bf2f((unsigned short)((M0)[i] & 0xFFFF));                         \
      float _hi = bf2f((unsigned short)((M0)[i] >> 16));                            \
      if (IN_MODE == 2) {                                                           \
        _lo += bf2f((unsigned short)((M1)[i] & 0xFFFF));                            \
        _hi += bf2f((unsigned short)((M1)[i] >> 16));                               \
      }                                                                             \
      _v[i] = cvtpk(_lo * ainv, _hi * ainv);                                        \
    }                                                                               \
    *(u32x4*)(dst) = _v;                                                            \
  }

  {
    const unsigned short* ap = Ain + (size_t)(row0 + sr) * 256 + seg * 8;
    u32x4 a0 = *(const u32x4*)ap;
    u32x4 a1 = (IN_MODE == 2) ? *(const u32x4*)(ap + 4194304) : a0;
    ACONV(&Al[0][sr * 32 + ((seg ^ ssw) << 3)], a0, a1);
    const float* wp = W + (size_t)(n0 + sr) * 256 + seg * 8;
    float4 x = *(const float4*)wp, y = *(const float4*)(wp + 4);
    u32x4 v; v[0] = cvtpk(x.x, x.y); v[1] = cvtpk(x.z, x.w);
    v[2] = cvtpk(y.x, y.y); v[3] = cvtpk(y.z, y.w);
    *(u32x4*)&Wl[0][sr * 32 + ((seg ^ ssw) << 3)] = v;
  }
  __syncthreads();

  f32x4 acc[4];
#pragma unroll
  for (int jt = 0; jt < 4; ++jt) acc[jt] = (f32x4){0.f, 0.f, 0.f, 0.f};

#pragma unroll 1
  for (int ch = 0; ch < 8; ++ch) {
    const int cur = ch & 1;
    const bool pre = (ch + 1 < 8);
    float4 wx, wy; u32x4 abv, abv2;
    if (pre) {
      const int ko = (ch + 1) * 32 + seg * 8;
      const unsigned short* ap = Ain + (size_t)(row0 + sr) * 256 + ko;
      abv = *(const u32x4*)ap;
      if (IN_MODE == 2) abv2 = *(const u32x4*)(ap + 4194304);
      const float* wp = W + (size_t)(n0 + sr) * 256 + ko;
      wx = *(const float4*)wp; wy = *(const float4*)(wp + 4);
    }
    const int ra = w * 16 + c;
    bf16x8 af = ldbf16(&Al[cur][ra * 32 + ((g ^ swz4(ra)) << 3)]);
#pragma unroll
    for (int jt = 0; jt < 4; ++jt) {
      const int j = jt * 16 + c;
      bf16x8 bfr = ldbf16(&Wl[cur][j * 32 + ((g ^ swz4(j)) << 3)]);
      acc[jt] = mfma16(af, bfr, acc[jt]);
    }
    if (pre) {
      ACONV(&Al[1 - cur][sr * 32 + ((seg ^ ssw) << 3)], abv, abv2);
      u32x4 vw; vw[0] = cvtpk(wx.x, wx.y); vw[1] = cvtpk(wx.z, wx.w);
      vw[2] = cvtpk(wy.x, wy.y); vw[3] = cvtpk(wy.z, wy.w);
      *(u32x4*)&Wl[1 - cur][sr * 32 + ((seg ^ ssw) << 3)] = vw;
    }
    __syncthreads();
  }
#undef ACONV

#pragma unroll
  for (int jt = 0; jt < 4; ++jt) {
    const int col = n0 + jt * 16 + c;
    const float bv = biasl[jt * 16 + c];
    const int rloc = w * 16 + (g << 2);
#pragma unroll
    for (int r = 0; r < 4; ++r)
      Cout[(size_t)(row0 + rloc + r) * 256 + col] = acc[jt][r] + bv;
  }
}

// ---------------- flash attention (R12, proven; alpha pre-folded into Q) ----------------
template <int NS>
__global__ __launch_bounds__(512, 2) void attn_k(const unsigned short* __restrict__ qg,
                                                 const unsigned short* __restrict__ kg,
                                                 const unsigned short* __restrict__ vg,
                                                 unsigned short* __restrict__ part,
                                                 float* __restrict__ lw) {
  __shared__ __align__(16) unsigned char smem[148480];
  const int tid = threadIdx.x, w = tid >> 6, l = tid & 63;
  const int l31 = l & 31, h5 = l >> 5;
  const int qt = w >> 1, hf = w & 1;   // QK role
  const int dh = w >> 1, qh = w & 1;   // PV role
  const int bid = blockIdx.x;
  const int b4 = bid & 3;
  const int s = (NS == 2) ? ((bid >> 2) & 1) : 0;
  const int qtl = (NS == 2) ? (bid >> 3) : (bid >> 2);
  const int q0 = qtl * 128;
  const int NT = (NS == 2) ? 32 : 64;

  const unsigned short* kb = kg + (size_t)b4 * 1048576 + (size_t)s * 524288;
  const unsigned short* vb = vg + (size_t)b4 * 1048576 + (size_t)s * 32 * 16384;

  bf16x8 qf[16];
  {
    const unsigned short* qp = qg + ((size_t)b4 * 4096 + q0 + qt * 32 + l31) * 256;
#pragma unroll
    for (int kst = 0; kst < 16; ++kst) qf[kst] = ldbf16(qp + kst * 16 + h5 * 8);
  }

  f32x16 o[4];
#pragma unroll
  for (int d = 0; d < 4; ++d)
#pragma unroll
    for (int r = 0; r < 16; ++r) o[d][r] = 0.f;
  float l_run = 0.f;

  int goffK[4], goffV[4];
#pragma unroll
  for (int i = 0; i < 4; ++i) {
    const int sl = i * 512 + tid;
    const int kk = sl >> 5, ch = sl & 31;
    goffK[i] = kk * 256 + ((ch ^ (kk & 31)) << 3);
    const int r = sl >> 4, p16 = sl & 15;
    const int x = p16 ^ (r & 15);
    goffV[i] = (2 * r + (x >> 3)) * 64 + ((x & 7) << 3);
  }
#define STAGE(buf, t1)                                                                   \
  {                                                                                      \
    const unsigned short* _ks = kb + (size_t)(t1) * 16384;                               \
    const unsigned short* _vs = vb + (size_t)(t1) * 16384;                               \
    _Pragma("unroll") for (int i = 0; i < 4; ++i)                                        \
        gld16(smem + (buf) * 32768 + i * 8192 + w * 1024, _ks + goffK[i]);               \
    _Pragma("unroll") for (int i = 0; i < 4; ++i)                                        \
        gld16(smem + 65536 + (buf) * 32768 + i * 8192 + w * 1024, _vs + goffV[i]);       \
  }

  STAGE(0, 0);
  __syncthreads();

  unsigned char* Pq = smem + 131072 + qt * 4096;
  const int kkr = hf * 32 + l31;

#pragma unroll 1
  for (int t = 0; t < NT; ++t) {
    const int cur = t & 1;
    if (t + 1 < NT) STAGE(1 - cur, t + 1);

    const unsigned char* Kc = smem + cur * 32768 + kkr * 512;
    f32x16 sa, sb;
#pragma unroll
    for (int r = 0; r < 16; ++r) { sa[r] = 0.f; sb[r] = 0.f; }
    __builtin_amdgcn_s_setprio(1);
#pragma unroll
    for (int kst = 0; kst < 16; ++kst) {
      bf16x8 kf = ldbf16(Kc + (((kst * 2 + h5) ^ l31) << 4));
      if (kst & 1) sb = mfma32(kf, qf[kst], sb);
      else         sa = mfma32(kf, qf[kst], sa);
    }
    __builtin_amdgcn_s_setprio(0);

    // ---- hoisted V-frag reads (V[cur] valid since bar2 of t-1): overlap softmax VALU
    const unsigned char* Vc = smem + 65536 + cur * 32768;
    bf16x8 va[8];
#pragma unroll
    for (int dd = 0; dd < 2; ++dd) {
      const int dm = dh * 64 + dd * 32 + l31;
      const int rr = dm >> 1;
      const unsigned char* Vr = Vc + rr * 256;
      const int xb = (dm & 1) * 8;
#pragma unroll
      for (int kst = 0; kst < 4; ++kst)
        va[dd * 4 + kst] = ldbf16(Vr + (((xb + kst * 2 + h5) ^ (rr & 15)) << 4));
    }

    float p[16];
#pragma unroll
    for (int r = 0; r < 16; ++r) p[r] = exp2f(sa[r] + sb[r]);  // alpha pre-folded into Q
    float ls = ((p[0] + p[1]) + (p[2] + p[3])) + ((p[4] + p[5]) + (p[6] + p[7])) +
               (((p[8] + p[9]) + (p[10] + p[11])) + ((p[12] + p[13]) + (p[14] + p[15])));
    l_run += ls;  // lane-local; cross-half reduce hoisted to after the loop

    unsigned u[8];
#pragma unroll
    for (int i = 0; i < 8; ++i) u[i] = cvtpk(p[2 * i], p[2 * i + 1]);
#pragma unroll
    for (int j = 0; j < 4; ++j) {
      u32x2 dv; dv[0] = u[2 * j]; dv[1] = u[2 * j + 1];
      *(u32x2*)(Pq + l31 * 128 + (((j + 4 * hf) ^ (l31 & 7)) << 4) + h5 * 8) = dv;
    }

    asm volatile("s_waitcnt lgkmcnt(0)\n\ts_barrier" ::: "memory");
    __builtin_amdgcn_sched_barrier(0);

    __builtin_amdgcn_s_setprio(1);
#pragma unroll
    for (int qq = 0; qq < 2; ++qq) {
      const unsigned char* Pr = smem + 131072 + (qh * 2 + qq) * 4096;
      bf16x8 pb[4];
#pragma unroll
      for (int kst = 0; kst < 4; ++kst)
        pb[kst] = ldbf16(Pr + l31 * 128 + (((kst * 2 + h5) ^ (l31 & 7)) << 4));
#pragma unroll
      for (int dd = 0; dd < 2; ++dd)
#pragma unroll
        for (int kst = 0; kst < 4; ++kst)
          o[dd * 2 + qq] = mfma32(va[dd * 4 + kst], pb[kst], o[dd * 2 + qq]);
    }
    __builtin_amdgcn_s_setprio(0);

    __syncthreads();
  }
#undef STAGE

  l_run += __shfl_xor(l_run, 32);  // hoisted cross-half l reduce

  float* Lb = (float*)(smem + 147456);
  if (l < 32) Lb[(qt * 2 + hf) * 32 + l31] = l_run;
  __syncthreads();

  unsigned char* T = smem + w * 16384;
#pragma unroll
  for (int dd = 0; dd < 2; ++dd)
#pragma unroll
    for (int qq = 0; qq < 2; ++qq)
#pragma unroll
      for (int rg = 0; rg < 4; ++rg) {
        f32x4 wv;
        wv[0] = o[dd * 2 + qq][4 * rg + 0]; wv[1] = o[dd * 2 + qq][4 * rg + 1];
        wv[2] = o[dd * 2 + qq][4 * rg + 2]; wv[3] = o[dd * 2 + qq][4 * rg + 3];
        const int qloc = qq * 32 + l31;
        const int c16 = dd * 8 + rg * 2 + h5;
        *(f32x4*)(T + qloc * 256 + ((c16 ^ (qloc & 15)) << 4)) = wv;
      }
  asm volatile("s_waitcnt lgkmcnt(0)" ::: "memory");
  __builtin_amdgcn_sched_barrier(0);
  {
    const int qloc = l;
    f32x4 rv[16];
#pragma unroll
    for (int c16 = 0; c16 < 16; ++c16)
      rv[c16] = *(const f32x4*)(T + qloc * 256 + ((c16 ^ (qloc & 15)) << 4));
    unsigned short* op = part + (size_t)s * 4194304 +
                         ((size_t)b4 * 4096 + q0 + qh * 64 + qloc) * 256 + dh * 64;
#pragma unroll
    for (int i = 0; i < 8; ++i) {
      u32x4 ov;
      ov[0] = cvtpk(rv[2 * i][0], rv[2 * i][1]);
      ov[1] = cvtpk(rv[2 * i][2], rv[2 * i][3]);
      ov[2] = cvtpk(rv[2 * i + 1][0], rv[2 * i + 1][1]);
      ov[3] = cvtpk(rv[2 * i + 1][2], rv[2 * i + 1][3]);
      *(u32x4*)(op + i * 8) = ov;
    }
  }
  if (hf == 0 && l < 32) {
    const float lt = Lb[(qt * 2) * 32 + l31] + Lb[(qt * 2 + 1) * 32 + l31];
    lw[(size_t)s * 16384 + (size_t)b4 * 4096 + q0 + qt * 32 + l31] = lt;
  }
}

extern "C" void kernel_launch(void* const* d_in, const int* in_sizes, int n_in,
                              void* d_out, int out_size, void* d_ws, size_t ws_size,
                              hipStream_t stream) {
  (void)in_sizes; (void)n_in; (void)out_size;
  const float* desc0 = (const float*)d_in[0];
  const float* desc1 = (const float*)d_in[1];
  const float* Wq = (const float*)d_in[2];
  const float* bq = (const float*)d_in[3];
  const float* Wk = (const float*)d_in[4];
  const float* bk = (const float*)d_in[5];
  const float* Wv = (const float*)d_in[6];
  const float* bv = (const float*)d_in[7];
  const float* Wo = (const float*)d_in[8];
  const float* bo = (const float*)d_in[9];

  unsigned char* ws = (unsigned char*)d_ws;
  unsigned short* qw = (unsigned short*)(ws);
  unsigned short* kw = (unsigned short*)(ws + 8388608);
  unsigned short* vw = (unsigned short*)(ws + 16777216);
  unsigned short* part = (unsigned short*)(ws + 25165824);
  float* lwp = (float*)(ws + 41943040);

  const bool two = (ws_size >= 42008576ull);

  qkv_k<<<2048, 256, 0, stream>>>(desc0, desc1, Wq, bq, Wk, bk, Wv, bv, qw, kw, vw);
  if (two) {
    attn_k<2><<<256, 512, 0, stream>>>(qw, kw, vw, part, lwp);
    projo_k<2><<<1024, 256, 0, stream>>>(part, Wo, bo, (float*)d_out, lwp);
  } else {
    lwp = (float*)(ws + 33554432);
    attn_k<1><<<128, 512, 0, stream>>>(qw, kw, vw, part, lwp);
    projo_k<3><<<1024, 256, 0, stream>>>(part, Wo, bo, (float*)d_out, lwp);
  }
}